// Round 7
// baseline (827.178 us; speedup 1.0000x reference)
//
#include <hip/hip_runtime.h>

// ===================== helpers =====================

__device__ __forceinline__ float bnscale(float g){ return g / sqrtf(1.0f + 1e-5f); }

__device__ __forceinline__ float conv_feat6(float p0,float p1,float p2,float p3,float p4,float p5,
                                            float w0,float w1,float w2,float w3,float w4,float w5,
                                            float sc,float bs){
    float y = p0*w0;
    y = fmaf(p1,w1,y); y = fmaf(p2,w2,y); y = fmaf(p3,w3,y);
    y = fmaf(p4,w4,y); y = fmaf(p5,w5,y);
    return fmaxf(fmaf(y,sc,bs), 0.0f);
}

// FPS distance: matches jnp.sum((p-c)**2, -1) left-to-right, NO contraction
__device__ __forceinline__ float fpsdist(float dx,float dy,float dz){
    #pragma clang fp contract(off)
    return (dx*dx + dy*dy) + dz*dz;
}

// square_distance(): d = (-2*dot + |q|^2) + |p|^2, left-to-right, NO contraction.
__device__ __forceinline__ float sumsq3(float x,float y,float z){
    #pragma clang fp contract(off)
    return (x*x + y*y) + z*z;
}
__device__ __forceinline__ float sqdist3(float qx,float qy,float qz,float qs,
                                         float px,float py,float pz){
    #pragma clang fp contract(off)
    {
        float dot = (qx*px + qy*py) + qz*pz;
        float pn  = (px*px + py*py) + pz*pz;
        return (-2.0f*dot + qs) + pn;
    }
}
// same, with pn precomputed (must equal sumsq3(px,py,pz) bitwise)
__device__ __forceinline__ float sqdist3_pn(float qx,float qy,float qz,float qs,
                                            float px,float py,float pz,float pn){
    #pragma clang fp contract(off)
    {
        float dot = (qx*px + qy*py) + qz*pz;
        return (-2.0f*dot + qs) + pn;
    }
}

// pack (dist,idx) into sortable u64: ascending u64 == ascending (dist, idx) lexicographic
__device__ __forceinline__ unsigned long long packdi(float d, unsigned int idx){
    unsigned int u = __float_as_uint(d);
    unsigned int msk = (unsigned int)((int)u >> 31);
    u ^= (msk | 0x80000000u);
    return ((unsigned long long)u << 32) | (unsigned long long)idx;
}

__device__ __forceinline__ unsigned long long u64min(unsigned long long a, unsigned long long b){
    return a < b ? a : b;
}

__device__ __forceinline__ unsigned long long u64_shfl_down(unsigned long long v, int off){
    unsigned int lo = (unsigned int)v, hi = (unsigned int)(v >> 32);
    lo = __shfl_down(lo, off, 64);
    hi = __shfl_down(hi, off, 64);
    return ((unsigned long long)hi << 32) | (unsigned long long)lo;
}

__device__ __forceinline__ unsigned long long u64_bcast0(unsigned long long v){
    unsigned int lo = (unsigned int)v, hi = (unsigned int)(v >> 32);
    lo = __shfl(lo, 0, 64);
    hi = __shfl(hi, 0, 64);
    return ((unsigned long long)hi << 32) | (unsigned long long)lo;
}

// ===================== k_fps1 =====================
// center + centered-coords precompute (float4 {x,y,z,|p|^2}) + FPS(16384->128).
// One block (512 thr) per batch. v6: the 128-float coord working set is NOT
// kept in registers (that spilled to AGPR/scratch in r4-r6); instead the FPS
// loop reloads 1 dwordx4 per point per iteration from the L2-resident xyzc
// buffer. dist[32] stays in arch VGPRs. asm memory clobber blocks LICM from
// hoisting the (loop-invariant-address) loads back into registers.
__global__ __launch_bounds__(512, 1) void k_fps1(const float* __restrict__ xyz,
                                                 float4* xyzc,
                                                 float* __restrict__ out,
                                                 int* __restrict__ idx_out){
    constexpr int NTH = 512, PPT = 32, N = 16384, NPOINT = 128, NW = 8;
    int b = blockIdx.x, t = threadIdx.x;
    int wid = t>>6, lane = t&63;

    __shared__ float s_red[NW][3];
    __shared__ unsigned int s_khi[2][NW], s_klo[2][NW];

    const float* xb = xyz + (size_t)b*N*3;
    float4* xc = xyzc + (size_t)b*N;

    // ---- pass A: block mean ----
    float sx=0.f, sy=0.f, sz=0.f;
    for (int i=0;i<PPT;i++){
        const float* sp = xb + (size_t)(t + i*NTH)*3;
        sx += sp[0]; sy += sp[1]; sz += sp[2];
    }
    #pragma unroll
    for (int off=32; off>=1; off>>=1){
        sx += __shfl_down(sx, off, 64);
        sy += __shfl_down(sy, off, 64);
        sz += __shfl_down(sz, off, 64);
    }
    if (lane==0){ s_red[wid][0]=sx; s_red[wid][1]=sy; s_red[wid][2]=sz; }
    __syncthreads();
    float cx0=0.f, cy0=0.f, cz0=0.f;
    #pragma unroll
    for (int w2=0; w2<NW; ++w2){ cx0+=s_red[w2][0]; cy0+=s_red[w2][1]; cz0+=s_red[w2][2]; }
    cx0 *= (1.0f/16384.0f); cy0 *= (1.0f/16384.0f); cz0 *= (1.0f/16384.0f);
    if (t < 3){
        float c = (t==0)?cx0:((t==1)?cy0:cz0);
        out[b*3+t] = c;           // output 0: center (32,3)
    }

    // ---- pass B: write centered coords + |p|^2 ----
    for (int i=0;i<PPT;i++){
        int n = t + i*NTH;
        const float* sp = xb + (size_t)n*3;
        float ax = sp[0]-cx0, ay = sp[1]-cy0, az = sp[2]-cz0;
        xc[n] = make_float4(ax, ay, az, sumsq3(ax,ay,az));
    }
    if (t==0) idx_out[b*NPOINT] = 0;

    float dist[PPT];
    #pragma unroll
    for (int i=0;i<PPT;i++) dist[i]=1e10f;

    float cx = xb[0]-cx0, cy = xb[1]-cy0, cz = xb[2]-cz0;
    __syncthreads();     // drain pass-B stores (compiler emits vmcnt(0) before barrier)

    for (int it=1; it<NPOINT; ++it){
        asm volatile("" ::: "memory");      // force per-iteration reload of xc
        int par = it & 1;
        float bv = -1.0f; int bis = 0;
        #pragma unroll
        for (int i=0;i<PPT;i++){
            float4 p = xc[t + i*NTH];
            float d = fpsdist(p.x-cx, p.y-cy, p.z-cz);
            float nd = fminf(dist[i], d);
            dist[i] = nd;
            bool better = nd > bv;          // strict > : lowest slot wins in-thread
            bv  = better ? nd : bv;
            bis = better ? i  : bis;
        }
        int bi = t + (bis<<9);              // flat index (NTH=512)
        unsigned long long key = ((unsigned long long)__float_as_uint(bv) << 32)
                               | (unsigned long long)(unsigned)(~(unsigned)bi);
        #pragma unroll
        for (int off=32; off>=1; off>>=1){
            unsigned long long ok = u64_shfl_down(key, off);
            key = ok > key ? ok : key;
        }
        if (lane==0){ s_khi[par][wid]=(unsigned)(key>>32); s_klo[par][wid]=(unsigned)key; }
        __syncthreads();
        unsigned long long gk = ((unsigned long long)s_khi[par][0] << 32) | s_klo[par][0];
        #pragma unroll
        for (int w2=1; w2<NW; ++w2){
            unsigned long long k2 = ((unsigned long long)s_khi[par][w2] << 32) | s_klo[par][w2];
            if (k2 > gk) gk = k2;
        }
        int gi = (int)(~(unsigned)(gk & 0xFFFFFFFFull));
        gi = __builtin_amdgcn_readfirstlane(gi);
        if (t==0) idx_out[b*NPOINT + it] = gi;
        const float* wp = xb + (size_t)gi*3;        // raw + sub: bit-identical
        cx = wp[0]-cx0; cy = wp[1]-cy0; cz = wp[2]-cz0;
    }
}

// ===================== k_knn1 (fused gather1 + knn, xyzc float4 loads) ==========
__global__ __launch_bounds__(256) void k_knn1(const float4* __restrict__ xyzc,
                                              const float* __restrict__ f,
                                              const float* __restrict__ conv1_w,
                                              const float* __restrict__ bn1_g,
                                              const float* __restrict__ bn1_b,
                                              const int* __restrict__ fps_idx,
                                              float* __restrict__ new_xyz,
                                              float* __restrict__ np_feat,
                                              int* __restrict__ knn_idx){
    int t = threadIdx.x, wid = t>>6, lane = t&63;
    int q = blockIdx.x*4 + wid;           // 0..4095
    int b = q>>7, s = q&127;

    int idx = fps_idx[b*128+s];
    const float4* xcb = xyzc + (size_t)b*16384;
    float4 qc = xcb[idx];
    float p0 = qc.x, p1 = qc.y, p2 = qc.z;
    const float* fp = f + ((size_t)b*16384 + idx)*3;
    float p3 = fp[0], p4 = fp[1], p5 = fp[2];

    {
        const float* w6 = conv1_w + lane*6;
        float v = conv_feat6(p0,p1,p2,p3,p4,p5, w6[0],w6[1],w6[2],w6[3],w6[4],w6[5],
                             bnscale(bn1_g[lane]), bn1_b[lane]);
        np_feat[(size_t)q*64 + lane] = v;
        if (lane < 3){
            float pc = (lane==0)?p0:((lane==1)?p1:p2);
            new_xyz[(size_t)q*3 + lane] = pc;
        }
    }

    float qx = p0, qy = p1, qz = p2;
    float qs = qc.w;                       // = sumsq3(p0,p1,p2) bitwise

    unsigned long long m0=~0ull, m1=~0ull, m2=~0ull, m3=~0ull;
    for (int i=0; i<256; i+=4){
        #pragma unroll
        for (int j=0;j<4;j++){
            int n = lane + ((i+j)<<6);
            float4 pc = xcb[n];
            float d = sqdist3_pn(qx,qy,qz,qs, pc.x,pc.y,pc.z, pc.w);
            unsigned long long pk = packdi(d,(unsigned)n);
            if (j==0) m0 = u64min(m0,pk);
            else if (j==1) m1 = u64min(m1,pk);
            else if (j==2) m2 = u64min(m2,pk);
            else m3 = u64min(m3,pk);
        }
    }

    size_t kbase = (size_t)q*32;
    for (int r=0; r<32; ++r){
        unsigned long long mm = u64min(u64min(m0,m1), u64min(m2,m3));
        #pragma unroll
        for (int off=32; off>=1; off>>=1) mm = u64min(mm, u64_shfl_down(mm, off));
        unsigned long long win = u64_bcast0(mm);
        unsigned int widx = (unsigned int)(win & 0xFFFFFFFFull);
        if (lane==0) knn_idx[kbase + r] = (int)widx;
        int c = (int)(widx & 255u);
        int n2 = c + (lane<<8);
        float4 pc = xcb[n2];
        float d = sqdist3_pn(qx,qy,qz,qs, pc.x,pc.y,pc.z, pc.w);
        unsigned long long pk = packdi(d,(unsigned)n2);
        if (pk <= win) pk = ~0ull;
        #pragma unroll
        for (int off=32; off>=1; off>>=1) pk = u64min(pk, u64_shfl_down(pk, off));
        unsigned long long nm = u64_bcast0(pk);
        int owner = c & 63, slot = c >> 6;
        if (lane == owner){
            if (slot==0) m0 = nm;
            else if (slot==1) m1 = nm;
            else if (slot==2) m2 = nm;
            else m3 = nm;
        }
    }
}

// ===================== k_group_local (stage 1; xyzc loads) =====================
template<int K, int NQ>
__global__ __launch_bounds__(256, 2) void k_group_local(
    const float4* __restrict__ xyzc, const float* __restrict__ f,
    const float* __restrict__ conv1_w, const float* __restrict__ bn1_g, const float* __restrict__ bn1_b,
    const int* __restrict__ knn_idx, const float* __restrict__ np_feat,
    const float* __restrict__ w, const float* __restrict__ g, const float* __restrict__ bb,
    float* __restrict__ out)
{
    __shared__ float wt[128*65];
    __shared__ float s_sc[64], s_bs[64];
    __shared__ float cwT[6*64];
    __shared__ float s_csc[64], s_cbs[64];
    __shared__ float np_l[4][64];
    __shared__ float gda[4][K][64];
    __shared__ float s_pts[4][K][6];

    int t = threadIdx.x;
    for (int e=t; e<8192; e+=256){ int o = e>>7, d = e&127; wt[d*65 + o] = w[e]; }
    if (t < 64){ s_sc[t] = bnscale(g[t]); s_bs[t] = bb[t]; }
    for (int e=t; e<384; e+=256){ int o = e/6, j = e%6; cwT[j*64 + o] = conv1_w[e]; }
    if (t < 64){ s_csc[t] = bnscale(bn1_g[t]); s_cbs[t] = bn1_b[t]; }
    __syncthreads();

    int wid = t>>6, lane = t&63;
    int q = blockIdx.x*4 + wid;
    int b = q / NQ, s = q % NQ;

    float np_o = np_feat[((size_t)b*NQ + s)*64 + lane];
    np_l[wid][lane] = np_o;

    const int* kix = knn_idx + ((size_t)b*NQ + s)*K;

    if (lane < K){
        int myi = kix[lane];
        float4 pc = xyzc[(size_t)b*16384 + myi];
        s_pts[wid][lane][0] = pc.x;
        s_pts[wid][lane][1] = pc.y;
        s_pts[wid][lane][2] = pc.z;
        const float* fp = f + ((size_t)b*16384 + myi)*3;
        s_pts[wid][lane][3] = fp[0];
        s_pts[wid][lane][4] = fp[1];
        s_pts[wid][lane][5] = fp[2];
    }
    #pragma unroll
    for (int k=0; k<K; ++k){
        float gv = conv_feat6(s_pts[wid][k][0], s_pts[wid][k][1], s_pts[wid][k][2],
                              s_pts[wid][k][3], s_pts[wid][k][4], s_pts[wid][k][5],
                              cwT[0*64+lane], cwT[1*64+lane], cwT[2*64+lane],
                              cwT[3*64+lane], cwT[4*64+lane], cwT[5*64+lane],
                              s_csc[lane], s_cbs[lane]);
        gda[wid][k][lane] = gv - np_o;
    }

    float C = 0.f;
    #pragma unroll
    for (int d=0; d<64; d++) C = fmaf(np_l[wid][d], wt[(64+d)*65 + lane], C);

    float acc_y[K];
    #pragma unroll
    for (int k=0;k<K;k++) acc_y[k] = C;

    #pragma unroll
    for (int c=0; c<2; ++c){
        float wr[32];
        #pragma unroll
        for (int j=0;j<32;j++) wr[j] = wt[(c*32+j)*65 + lane];
        #pragma unroll
        for (int k=0;k<K;k++){
            const float4* g4 = (const float4*)&gda[wid][k][c*32];
            float yk = 0.f;
            #pragma unroll
            for (int j4=0;j4<8;j4++){
                float4 gg = g4[j4];
                yk = fmaf(gg.x, wr[j4*4+0], yk);
                yk = fmaf(gg.y, wr[j4*4+1], yk);
                yk = fmaf(gg.z, wr[j4*4+2], yk);
                yk = fmaf(gg.w, wr[j4*4+3], yk);
            }
            acc_y[k] = acc_y[k] + yk;
        }
    }

    float acc = -1e30f;
    #pragma unroll
    for (int k=0;k<K;k++){
        float v = fmaxf(fmaf(acc_y[k], s_sc[lane], s_bs[lane]), 0.0f);
        acc = fmaxf(acc, v);
    }
    out[((size_t)b*NQ + s)*64 + lane] = acc;
}

// ===================== sa_block (512-thr, wave-parallel softmax) ================
__device__ void sa_block(const float* X, float* Xout,
                         float* Q, float* E, float* XV, float* XR, float* CS,
                         const float* qk_w, const float* v_w, const float* v_b,
                         const float* t_w, const float* t_b,
                         const float* g, const float* bb, int t)
{
    constexpr int NT = 512;
    for (int e=t; e<512; e+=NT){
        int n = e>>4, o = e&15;
        float y = 0.f;
        for (int c=0;c<64;c++) y = fmaf(qk_w[o*64+c], X[c*32+n], y);
        Q[n*16+o] = y;
    }
    for (int e=t; e<2048; e+=NT){
        int o = e>>5, n = e&31;
        float y = v_b[o];
        for (int c=0;c<64;c++) y = fmaf(v_w[o*64+c], X[c*32+n], y);
        XV[o*32+n] = y;
    }
    __syncthreads();
    for (int e=t; e<1024; e+=NT){
        int n = e>>5, m = e&31;
        float y = 0.f;
        for (int d=0;d<16;d++) y = fmaf(Q[n*16+d], Q[m*16+d], y);
        E[e] = y;
    }
    __syncthreads();
    // wave-parallel row softmax: each 32-lane group holds one row
    for (int e=t; e<1024; e+=NT){
        float v = E[e];
        float mx = v;
        #pragma unroll
        for (int mk=16; mk>=1; mk>>=1) mx = fmaxf(mx, __shfl_xor(mx, mk, 64));
        float p = expf(v - mx);
        float sum = p;
        #pragma unroll
        for (int mk=16; mk>=1; mk>>=1) sum += __shfl_xor(sum, mk, 64);
        E[e] = p / sum;
    }
    __syncthreads();
    if (t < 32){
        float cs = 0.f;
        for (int n=0;n<32;n++) cs += E[n*32+t];
        CS[t] = 1e-9f + cs;
    }
    __syncthreads();
    for (int e=t; e<1024; e+=NT) E[e] = E[e] / CS[e&31];
    __syncthreads();
    for (int e=t; e<2048; e+=NT){
        int c = e>>5, m = e&31;
        float y = 0.f;
        for (int n=0;n<32;n++) y = fmaf(XV[c*32+n], E[n*32+m], y);
        XR[c*32+m] = y;
    }
    __syncthreads();
    for (int e=t; e<2048; e+=NT){
        int o = e>>5, n = e&31;
        float y = 0.f;
        for (int c=0;c<64;c++) y = fmaf(t_w[o*64+c], X[c*32+n]-XR[c*32+n], y);
        y += t_b[o];
        y = fmaxf(fmaf(y, bnscale(g[o]), bb[o]), 0.0f);
        Xout[e] = X[e] + y;
    }
    __syncthreads();
}

// ===================== k_mega =====================
// fps2 + gather2 + knn2 + group_local<16> + tail. One block per batch.
// v3: 512 threads with (512,1) -> 8 waves (2/SIMD) for latency hiding AND a
// 512-VGPR budget (r6's plain (1024) capped at 64 VGPR -> 21.5 MB scratch).
__global__ __launch_bounds__(512, 1) void k_mega(
    const float* __restrict__ new_xyz1,   // (b,128,3) centered
    const float* __restrict__ feat,       // (b,128,64)
    const float* __restrict__ l1_w, const float* __restrict__ l1_g, const float* __restrict__ l1_b,
    const float* st_c1_w, const float* st_bn1_g, const float* st_bn1_b,
    const float* st_c2_w, const float* st_bn2_g, const float* st_bn2_b,
    const float* sa1_qk, const float* sa1_v, const float* sa1_vb,
    const float* sa1_t, const float* sa1_tb, const float* sa1_g, const float* sa1_b,
    const float* sa2_qk, const float* sa2_v, const float* sa2_vb,
    const float* sa2_t, const float* sa2_tb, const float* sa2_g, const float* sa2_b,
    const float* fuse_w, const float* fuse_g, const float* fuse_b,
    const float* lin1_w, const float* bn6_g, const float* bn6_b,
    const float* lin2_w, const float* lin2_b,
    float* __restrict__ out)
{
    constexpr int NT = 512;
    __shared__ float nx1[384];
    __shared__ int   s_i2[32];
    __shared__ float np2L[2048];
    __shared__ float nx2[96];
    __shared__ int   s_k2[512];
    __shared__ float wt[8320];
    __shared__ float s_sc[64], s_bs[64];
    __shared__ float smt[15168];          // tail scratch; F1 (stride 33) at 0

    int b = blockIdx.x, t = threadIdx.x, wid = t>>6, lane = t&63;

    // ---- A: stage ----
    for (int e=t; e<384; e+=NT) nx1[e] = new_xyz1[(size_t)b*384 + e];
    for (int e=t; e<8192; e+=NT){ int o = e>>7, d = e&127; wt[d*65 + o] = l1_w[e]; }
    if (t < 64){ s_sc[t] = bnscale(l1_g[t]); s_bs[t] = l1_b[t]; }
    __syncthreads();

    // ---- B: fps2 (128 -> 32), wave 0 only ----
    if (wid == 0){
        float px[2],py[2],pz[2],dist[2];
        #pragma unroll
        for (int i=0;i<2;i++){
            int n = lane + i*64;
            px[i]=nx1[n*3+0]; py[i]=nx1[n*3+1]; pz[i]=nx1[n*3+2];
            dist[i]=1e10f;
        }
        if (lane==0) s_i2[0] = 0;
        float cx=nx1[0], cy=nx1[1], cz=nx1[2];
        for (int it=1; it<32; ++it){
            float bv=-1.0f; int bi=0;
            float bx=0.f, by=0.f, bz=0.f;
            #pragma unroll
            for (int i=0;i<2;i++){
                float d = fpsdist(px[i]-cx, py[i]-cy, pz[i]-cz);
                float nd = fminf(dist[i], d);
                dist[i]=nd;
                bool better = nd > bv;
                bv = better ? nd : bv;
                bi = better ? (lane + i*64) : bi;
                bx = better ? px[i] : bx;
                by = better ? py[i] : by;
                bz = better ? pz[i] : bz;
            }
            unsigned long long key = ((unsigned long long)__float_as_uint(bv) << 32)
                                   | (unsigned long long)(unsigned)(~(unsigned)bi);
            #pragma unroll
            for (int off=32; off>=1; off>>=1){
                unsigned long long ok = u64_shfl_down(key, off);
                float ox = __shfl_down(bx, off, 64);
                float oy = __shfl_down(by, off, 64);
                float oz = __shfl_down(bz, off, 64);
                bool better = ok > key;
                key = better ? ok : key;
                bx = better ? ox : bx;
                by = better ? oy : by;
                bz = better ? oz : bz;
            }
            key = u64_bcast0(key);
            cx = __shfl(bx, 0, 64); cy = __shfl(by, 0, 64); cz = __shfl(bz, 0, 64);
            if (lane==0) s_i2[it] = (int)(~(unsigned)(key & 0xFFFFFFFFull));
        }
    }
    __syncthreads();

    // ---- C: gather2 ----
    for (int e=t; e<2048; e+=NT){
        int s = e>>6, o = e&63;
        np2L[s*64 + o] = feat[((size_t)b*128 + s_i2[s])*64 + o];
    }
    if (t < 32){
        int idx = s_i2[t];
        nx2[t*3+0] = nx1[idx*3+0];
        nx2[t*3+1] = nx1[idx*3+1];
        nx2[t*3+2] = nx1[idx*3+2];
    }
    __syncthreads();

    // ---- D: knn2 (32 queries x top-16 of 128), 4 queries per wave ----
    for (int j=0;j<4;j++){
        int s = wid + 8*j;
        float qx = nx2[s*3+0], qy = nx2[s*3+1], qz = nx2[s*3+2];
        float qs = sumsq3(qx,qy,qz);
        unsigned long long pp0, pp1;
        {
            float ax=nx1[lane*3+0], ay=nx1[lane*3+1], az=nx1[lane*3+2];
            pp0 = packdi(sqdist3(qx,qy,qz,qs,ax,ay,az), (unsigned)lane);
            ax=nx1[(lane+64)*3+0]; ay=nx1[(lane+64)*3+1]; az=nx1[(lane+64)*3+2];
            pp1 = packdi(sqdist3(qx,qy,qz,qs,ax,ay,az), (unsigned)(lane+64));
        }
        for (int r=0; r<16; ++r){
            unsigned long long mm = u64min(pp0, pp1);
            #pragma unroll
            for (int off=32; off>=1; off>>=1) mm = u64min(mm, u64_shfl_down(mm, off));
            unsigned long long win = u64_bcast0(mm);
            if (lane==0) s_k2[s*16 + r] = (int)(win & 0xFFFFFFFFull);
            if (pp0 == win) pp0 = ~0ull;
            if (pp1 == win) pp1 = ~0ull;
        }
    }
    __syncthreads();

    // ---- E: group_local<16>, 4 queries per wave ----
    float* gda = smt + 2112;     // aliases XA/XB (4096 floats), dead until tail
    for (int j=0;j<4;j++){
        int s = wid + 8*j;
        float np_o = np2L[s*64 + lane];
        float C0 = 0.f;
        #pragma unroll
        for (int d=0; d<64; d++) C0 = fmaf(np2L[s*64 + d], wt[(64+d)*65 + lane], C0);
        float acc_y[16];
        #pragma unroll
        for (int k=0;k<16;k++) acc_y[k] = C0;
        #pragma unroll
        for (int half=0; half<2; ++half){
            #pragma unroll
            for (int kk=0;kk<8;++kk){
                int ik = s_k2[s*16 + half*8 + kk];
                gda[(wid*8+kk)*64 + lane] = feat[((size_t)b*128 + ik)*64 + lane] - np_o;
            }
            #pragma unroll
            for (int c=0; c<2; ++c){
                float wr[32];
                #pragma unroll
                for (int jj=0;jj<32;jj++) wr[jj] = wt[(c*32+jj)*65 + lane];
                #pragma unroll
                for (int kk=0;kk<8;++kk){
                    const float4* g4 = (const float4*)&gda[(wid*8+kk)*64 + c*32];
                    float yk = 0.f;
                    #pragma unroll
                    for (int j4=0;j4<8;j4++){
                        float4 gg = g4[j4];
                        yk = fmaf(gg.x, wr[j4*4+0], yk);
                        yk = fmaf(gg.y, wr[j4*4+1], yk);
                        yk = fmaf(gg.z, wr[j4*4+2], yk);
                        yk = fmaf(gg.w, wr[j4*4+3], yk);
                    }
                    acc_y[half*8+kk] = acc_y[half*8+kk] + yk;
                }
            }
        }
        float acc = -1e30f;
        #pragma unroll
        for (int k=0;k<16;k++){
            float v = fmaxf(fmaf(acc_y[k], s_sc[lane], s_bs[lane]), 0.0f);
            acc = fmaxf(acc, v);
        }
        smt[lane*33 + s] = acc;     // F1[c=lane][n=s], stride 33
    }
    __syncthreads();

    // ---- F: tail ----
    float* F1 = smt;            // stride 33, [0,2112)
    float* XA = smt + 2112;
    float* XB = smt + 4160;
    float* Q  = smt + 6208;
    float* E  = smt + 6720;
    float* XV = smt + 7744;
    float* XR = smt + 9792;
    float* CS = smt + 11840;
    float* FO = smt + 6208;     // 256x33 = 8448 (reuses SA scratch)
    float* PO = smt + 14656;
    float* P2 = smt + 14912;

    for (int e=t; e<2048; e+=NT){
        int o = e>>5, n = e&31;
        float y = 0.f;
        for (int c=0;c<64;c++) y = fmaf(st_c1_w[o*64+c], F1[c*33+n], y);
        XA[e] = fmaxf(fmaf(y, bnscale(st_bn1_g[o]), st_bn1_b[o]), 0.0f);
    }
    __syncthreads();
    for (int e=t; e<2048; e+=NT){
        int o = e>>5, n = e&31;
        float y = 0.f;
        for (int c=0;c<64;c++) y = fmaf(st_c2_w[o*64+c], XA[c*32+n], y);
        XB[e] = fmaxf(fmaf(y, bnscale(st_bn2_g[o]), st_bn2_b[o]), 0.0f);
    }
    __syncthreads();
    sa_block(XB, XA, Q,E,XV,XR,CS, sa1_qk, sa1_v, sa1_vb, sa1_t, sa1_tb, sa1_g, sa1_b, t);
    sa_block(XA, XB, Q,E,XV,XR,CS, sa2_qk, sa2_v, sa2_vb, sa2_t, sa2_tb, sa2_g, sa2_b, t);
    for (int e=t; e<8192; e+=NT){
        int o = e>>5, n = e&31;
        const float* wr = fuse_w + o*192;
        float y = 0.f;
        for (int c=0;c<64;c++) y = fmaf(wr[c],      XA[c*32+n], y);
        for (int c=0;c<64;c++) y = fmaf(wr[64+c],   XB[c*32+n], y);
        for (int c=0;c<64;c++) y = fmaf(wr[128+c],  F1[c*33+n], y);
        float v = fmaf(y, bnscale(fuse_g[o]), fuse_b[o]);
        FO[o*33+n] = (v > 0.0f) ? v : 0.2f*v;
    }
    __syncthreads();
    if (t < 256){
        float mx = -1e30f;
        for (int n=0;n<32;n++) mx = fmaxf(mx, FO[t*33+n]);
        PO[t] = mx;
    }
    __syncthreads();
    if (t < 256){
        const float* wr = lin1_w + t*256;
        float y = 0.f;
        for (int c=0;c<256;c++) y = fmaf(wr[c], PO[c], y);
        P2[t] = fmaxf(fmaf(y, bnscale(bn6_g[t]), bn6_b[t]), 0.0f);
    }
    __syncthreads();
    if (t < 256){
        const float* wr = lin2_w + t*256;
        float y = 0.f;
        for (int c=0;c<256;c++) y = fmaf(wr[c], P2[c], y);
        out[96 + b*256 + t] = y + lin2_b[t];
    }
}

// ===================== launch =====================
extern "C" void kernel_launch(void* const* d_in, const int* in_sizes, int n_in,
                              void* d_out, int out_size, void* d_ws, size_t ws_size,
                              hipStream_t stream)
{
    const float* xyz      = (const float*)d_in[0];
    const float* f        = (const float*)d_in[1];
    const float* conv1_w  = (const float*)d_in[2];
    const float* bn1_g    = (const float*)d_in[3];
    const float* bn1_b    = (const float*)d_in[4];
    const float* l0_w     = (const float*)d_in[5];
    const float* l0_g     = (const float*)d_in[6];
    const float* l0_b     = (const float*)d_in[7];
    const float* l1_w     = (const float*)d_in[8];
    const float* l1_g     = (const float*)d_in[9];
    const float* l1_b     = (const float*)d_in[10];
    const float* st_c1_w  = (const float*)d_in[11];
    const float* st_bn1_g = (const float*)d_in[12];
    const float* st_bn1_b = (const float*)d_in[13];
    const float* st_c2_w  = (const float*)d_in[14];
    const float* st_bn2_g = (const float*)d_in[15];
    const float* st_bn2_b = (const float*)d_in[16];
    const float* sa1_qk   = (const float*)d_in[17];
    const float* sa1_v    = (const float*)d_in[18];
    const float* sa1_vb   = (const float*)d_in[19];
    const float* sa1_t    = (const float*)d_in[20];
    const float* sa1_tb   = (const float*)d_in[21];
    const float* sa1_g    = (const float*)d_in[22];
    const float* sa1_b    = (const float*)d_in[23];
    const float* sa2_qk   = (const float*)d_in[24];
    const float* sa2_v    = (const float*)d_in[25];
    const float* sa2_vb   = (const float*)d_in[26];
    const float* sa2_t    = (const float*)d_in[27];
    const float* sa2_tb   = (const float*)d_in[28];
    const float* sa2_g    = (const float*)d_in[29];
    const float* sa2_b    = (const float*)d_in[30];
    const float* fuse_w   = (const float*)d_in[31];
    const float* fuse_g   = (const float*)d_in[32];
    const float* fuse_b   = (const float*)d_in[33];
    const float* lin1_w   = (const float*)d_in[34];
    const float* bn6_g    = (const float*)d_in[35];
    const float* bn6_b    = (const float*)d_in[36];
    const float* lin2_w   = (const float*)d_in[37];
    const float* lin2_b   = (const float*)d_in[38];
    float* out = (float*)d_out;

    float* ws = (float*)d_ws;
    float4* xyzc    = (float4*)ws;                 // 16384*32 float4 = 2,097,152 floats
    float* new_xyz1 = ws + 2097152;                // 12288
    float* np1      = ws + 2109440;                // 262144
    float* feat     = ws + 2371584;                // 262144
    int*   fps1     = (int*)(ws + 2633728);        // 4096
    int*   knn1     = (int*)(ws + 2637824);        // 131072  (end ~11.1 MB)

    k_fps1<<<32, 512, 0, stream>>>(xyz, xyzc, out, fps1);
    k_knn1<<<1024, 256, 0, stream>>>(xyzc, f, conv1_w, bn1_g, bn1_b,
                                     fps1, new_xyz1, np1, knn1);
    k_group_local<32,128><<<1024, 256, 0, stream>>>(
        xyzc, f, conv1_w, bn1_g, bn1_b, knn1, np1, l0_w, l0_g, l0_b, feat);
    k_mega<<<32, 512, 0, stream>>>(new_xyz1, feat,
        l1_w, l1_g, l1_b,
        st_c1_w, st_bn1_g, st_bn1_b, st_c2_w, st_bn2_g, st_bn2_b,
        sa1_qk, sa1_v, sa1_vb, sa1_t, sa1_tb, sa1_g, sa1_b,
        sa2_qk, sa2_v, sa2_vb, sa2_t, sa2_tb, sa2_g, sa2_b,
        fuse_w, fuse_g, fuse_b, lin1_w, bn6_g, bn6_b, lin2_w, lin2_b, out);
}

// Round 9
// 679.781 us; speedup vs baseline: 1.2168x; 1.2168x over previous
//
#include <hip/hip_runtime.h>

// ===================== helpers =====================

__device__ __forceinline__ float bnscale(float g){ return g / sqrtf(1.0f + 1e-5f); }

__device__ __forceinline__ float conv_feat6(float p0,float p1,float p2,float p3,float p4,float p5,
                                            float w0,float w1,float w2,float w3,float w4,float w5,
                                            float sc,float bs){
    float y = p0*w0;
    y = fmaf(p1,w1,y); y = fmaf(p2,w2,y); y = fmaf(p3,w3,y);
    y = fmaf(p4,w4,y); y = fmaf(p5,w5,y);
    return fmaxf(fmaf(y,sc,bs), 0.0f);
}

// FPS distance: matches jnp.sum((p-c)**2, -1) left-to-right, NO contraction
__device__ __forceinline__ float fpsdist(float dx,float dy,float dz){
    #pragma clang fp contract(off)
    return (dx*dx + dy*dy) + dz*dz;
}

// square_distance(): d = (-2*dot + |q|^2) + |p|^2, left-to-right, NO contraction.
__device__ __forceinline__ float sumsq3(float x,float y,float z){
    #pragma clang fp contract(off)
    return (x*x + y*y) + z*z;
}
__device__ __forceinline__ float sqdist3(float qx,float qy,float qz,float qs,
                                         float px,float py,float pz){
    #pragma clang fp contract(off)
    {
        float dot = (qx*px + qy*py) + qz*pz;
        float pn  = (px*px + py*py) + pz*pz;
        return (-2.0f*dot + qs) + pn;
    }
}

// pack (dist,idx) into sortable u64: ascending u64 == ascending (dist, idx) lexicographic
__device__ __forceinline__ unsigned long long packdi(float d, unsigned int idx){
    unsigned int u = __float_as_uint(d);
    unsigned int msk = (unsigned int)((int)u >> 31);
    u ^= (msk | 0x80000000u);
    return ((unsigned long long)u << 32) | (unsigned long long)idx;
}

__device__ __forceinline__ unsigned long long u64min(unsigned long long a, unsigned long long b){
    return a < b ? a : b;
}

__device__ __forceinline__ unsigned long long u64_shfl_down(unsigned long long v, int off){
    unsigned int lo = (unsigned int)v, hi = (unsigned int)(v >> 32);
    lo = __shfl_down(lo, off, 64);
    hi = __shfl_down(hi, off, 64);
    return ((unsigned long long)hi << 32) | (unsigned long long)lo;
}

__device__ __forceinline__ unsigned long long u64_bcast0(unsigned long long v){
    unsigned int lo = (unsigned int)v, hi = (unsigned int)(v >> 32);
    lo = __shfl(lo, 0, 64);
    hi = __shfl(hi, 0, 64);
    return ((unsigned long long)hi << 32) | (unsigned long long)lo;
}

// ===================== k_fps1 =====================
// Merged center-compute + FPS(16384->128). One block (512 thr) per batch.
// (512,1): only 1 block/CU exists anyway (grid=32 on 256 CUs), so take the
// full 256-VGPR budget -> px/py/pz/dist[32] fully register-resident, no
// AGPR shuffling (round-4's (512,2) spilled at 128 budget; round-7's
// LDS/L2 reload variants were load-throughput-bound).
__global__ __launch_bounds__(512, 1) void k_fps1(const float* __restrict__ xyz,
                                                 float* __restrict__ center,
                                                 float* __restrict__ out,
                                                 int* __restrict__ idx_out){
    constexpr int NTH = 512, PPT = 32, N = 16384, NPOINT = 128, NW = 8;
    int b = blockIdx.x, t = threadIdx.x;
    int wid = t>>6, lane = t&63;

    __shared__ float s_red[NW][3];
    __shared__ unsigned int s_khi[2][NW], s_klo[2][NW];

    const float* xb = xyz + (size_t)b*N*3;
    float px[PPT], py[PPT], pz[PPT], dist[PPT];
    #pragma unroll
    for (int i=0;i<PPT;i++){
        const float* sp = xb + (size_t)(t + i*NTH)*3;
        px[i]=sp[0]; py[i]=sp[1]; pz[i]=sp[2];
        dist[i]=1e10f;
    }
    // ---- block mean (center) ----
    float sx=0.f, sy=0.f, sz=0.f;
    #pragma unroll
    for (int i=0;i<PPT;i++){ sx+=px[i]; sy+=py[i]; sz+=pz[i]; }
    #pragma unroll
    for (int off=32; off>=1; off>>=1){
        sx += __shfl_down(sx, off, 64);
        sy += __shfl_down(sy, off, 64);
        sz += __shfl_down(sz, off, 64);
    }
    if (lane==0){ s_red[wid][0]=sx; s_red[wid][1]=sy; s_red[wid][2]=sz; }
    __syncthreads();
    float cx0=0.f, cy0=0.f, cz0=0.f;
    #pragma unroll
    for (int w2=0; w2<NW; ++w2){ cx0+=s_red[w2][0]; cy0+=s_red[w2][1]; cz0+=s_red[w2][2]; }
    cx0 *= (1.0f/16384.0f); cy0 *= (1.0f/16384.0f); cz0 *= (1.0f/16384.0f);
    if (t < 3){
        float c = (t==0)?cx0:((t==1)?cy0:cz0);
        center[b*3+t] = c;
        out[b*3+t] = c;           // output 0: center (32,3)
    }
    #pragma unroll
    for (int i=0;i<PPT;i++){ px[i]-=cx0; py[i]-=cy0; pz[i]-=cz0; }
    if (t==0) idx_out[b*NPOINT] = 0;

    float cx = xb[0]-cx0, cy = xb[1]-cy0, cz = xb[2]-cz0;

    for (int it=1; it<NPOINT; ++it){
        int par = it & 1;
        // ---- dist update + in-thread argmax (small-slot index) ----
        float bv = -1.0f; int bis = 0;
        #pragma unroll
        for (int i=0;i<PPT;i++){
            float d = fpsdist(px[i]-cx, py[i]-cy, pz[i]-cz);
            float nd = fminf(dist[i], d);
            dist[i] = nd;
            bool better = nd > bv;          // strict > : lowest slot wins in-thread
            bv  = better ? nd : bv;
            bis = better ? i  : bis;        // i is an inline const per unrolled step
        }
        int bi = t + (bis<<9);              // flat index (NTH=512)
        // ---- key-only wave reduce (bv>=0 so raw bits order; ~bi -> lowest idx wins) ----
        unsigned long long key = ((unsigned long long)__float_as_uint(bv) << 32)
                               | (unsigned long long)(unsigned)(~(unsigned)bi);
        #pragma unroll
        for (int off=32; off>=1; off>>=1){
            unsigned long long ok = u64_shfl_down(key, off);
            key = ok > key ? ok : key;
        }
        if (lane==0){ s_khi[par][wid]=(unsigned)(key>>32); s_klo[par][wid]=(unsigned)key; }
        __syncthreads();
        unsigned long long gk = ((unsigned long long)s_khi[par][0] << 32) | s_klo[par][0];
        #pragma unroll
        for (int w2=1; w2<NW; ++w2){
            unsigned long long k2 = ((unsigned long long)s_khi[par][w2] << 32) | s_klo[par][w2];
            if (k2 > gk) gk = k2;
        }
        int gi = (int)(~(unsigned)(gk & 0xFFFFFFFFull));
        gi = __builtin_amdgcn_readfirstlane(gi);
        if (t==0) idx_out[b*NPOINT + it] = gi;
        const float* wp = xb + (size_t)gi*3;   // uniform broadcast load, bit-identical expr
        cx = wp[0]-cx0; cy = wp[1]-cy0; cz = wp[2]-cz0;
    }
}

// ===================== k_knn1 (fused gather1 + knn; raw xyz, proven r5/r6) ======
__global__ __launch_bounds__(256) void k_knn1(const float* __restrict__ xyz,
                                              const float* __restrict__ f,
                                              const float* __restrict__ center,
                                              const float* __restrict__ conv1_w,
                                              const float* __restrict__ bn1_g,
                                              const float* __restrict__ bn1_b,
                                              const int* __restrict__ fps_idx,
                                              float* __restrict__ new_xyz,
                                              float* __restrict__ np_feat,
                                              int* __restrict__ knn_idx){
    int t = threadIdx.x, wid = t>>6, lane = t&63;
    int q = blockIdx.x*4 + wid;           // 0..4095
    int b = q>>7, s = q&127;

    float cx = center[b*3+0], cy = center[b*3+1], cz = center[b*3+2];
    int idx = fps_idx[b*128+s];
    const float* xp = xyz + ((size_t)b*16384 + idx)*3;
    const float* fp = f   + ((size_t)b*16384 + idx)*3;
    float p0 = xp[0]-cx, p1 = xp[1]-cy, p2 = xp[2]-cz;
    float p3 = fp[0], p4 = fp[1], p5 = fp[2];

    {
        const float* w6 = conv1_w + lane*6;
        float v = conv_feat6(p0,p1,p2,p3,p4,p5, w6[0],w6[1],w6[2],w6[3],w6[4],w6[5],
                             bnscale(bn1_g[lane]), bn1_b[lane]);
        np_feat[(size_t)q*64 + lane] = v;
        if (lane < 3){
            float pc = (lane==0)?p0:((lane==1)?p1:p2);
            new_xyz[(size_t)q*3 + lane] = pc;
        }
    }

    float qx = p0, qy = p1, qz = p2;
    float qs = sumsq3(qx,qy,qz);
    const float* xb = xyz + (size_t)b*16384*3;

    unsigned long long m0=~0ull, m1=~0ull, m2=~0ull, m3=~0ull;
    for (int i=0; i<256; i+=4){
        #pragma unroll
        for (int j=0;j<4;j++){
            int n = lane + ((i+j)<<6);
            const float* p = xb + (size_t)n*3;
            float dx = p[0]-cx, dy = p[1]-cy, dz = p[2]-cz;
            float d = sqdist3(qx,qy,qz,qs,dx,dy,dz);
            unsigned long long pk = packdi(d,(unsigned)n);
            if (j==0) m0 = u64min(m0,pk);
            else if (j==1) m1 = u64min(m1,pk);
            else if (j==2) m2 = u64min(m2,pk);
            else m3 = u64min(m3,pk);
        }
    }

    size_t kbase = (size_t)q*32;
    for (int r=0; r<32; ++r){
        unsigned long long mm = u64min(u64min(m0,m1), u64min(m2,m3));
        #pragma unroll
        for (int off=32; off>=1; off>>=1) mm = u64min(mm, u64_shfl_down(mm, off));
        unsigned long long win = u64_bcast0(mm);
        unsigned int widx = (unsigned int)(win & 0xFFFFFFFFull);
        if (lane==0) knn_idx[kbase + r] = (int)widx;
        int c = (int)(widx & 255u);
        int n2 = c + (lane<<8);
        const float* p = xb + (size_t)n2*3;
        float dx = p[0]-cx, dy = p[1]-cy, dz = p[2]-cz;
        float d = sqdist3(qx,qy,qz,qs,dx,dy,dz);
        unsigned long long pk = packdi(d,(unsigned)n2);
        if (pk <= win) pk = ~0ull;
        #pragma unroll
        for (int off=32; off>=1; off>>=1) pk = u64min(pk, u64_shfl_down(pk, off));
        unsigned long long nm = u64_bcast0(pk);
        int owner = c & 63, slot = c >> 6;
        if (lane == owner){
            if (slot==0) m0 = nm;
            else if (slot==1) m1 = nm;
            else if (slot==2) m2 = nm;
            else m3 = nm;
        }
    }
}

// ===================== k_group_local (stage 1; proven r5/r6) =====================
template<int K, int NQ>
__global__ __launch_bounds__(256, 2) void k_group_local(
    const float* __restrict__ xyz, const float* __restrict__ f, const float* __restrict__ center,
    const float* __restrict__ conv1_w, const float* __restrict__ bn1_g, const float* __restrict__ bn1_b,
    const int* __restrict__ knn_idx, const float* __restrict__ np_feat,
    const float* __restrict__ w, const float* __restrict__ g, const float* __restrict__ bb,
    float* __restrict__ out)
{
    __shared__ float wt[128*65];
    __shared__ float s_sc[64], s_bs[64];
    __shared__ float cwT[6*64];
    __shared__ float s_csc[64], s_cbs[64];
    __shared__ float np_l[4][64];
    __shared__ float gda[4][K][64];
    __shared__ float s_pts[4][K][6];

    int t = threadIdx.x;
    for (int e=t; e<8192; e+=256){ int o = e>>7, d = e&127; wt[d*65 + o] = w[e]; }
    if (t < 64){ s_sc[t] = bnscale(g[t]); s_bs[t] = bb[t]; }
    for (int e=t; e<384; e+=256){ int o = e/6, j = e%6; cwT[j*64 + o] = conv1_w[e]; }
    if (t < 64){ s_csc[t] = bnscale(bn1_g[t]); s_cbs[t] = bn1_b[t]; }
    __syncthreads();

    int wid = t>>6, lane = t&63;
    int q = blockIdx.x*4 + wid;
    int b = q / NQ, s = q % NQ;

    float np_o = np_feat[((size_t)b*NQ + s)*64 + lane];
    np_l[wid][lane] = np_o;

    const int* kix = knn_idx + ((size_t)b*NQ + s)*K;

    float cx = center[b*3+0], cy = center[b*3+1], cz = center[b*3+2];
    if (lane < K){
        int myi = kix[lane];
        const float* xp = xyz + ((size_t)b*16384 + myi)*3;
        s_pts[wid][lane][0] = xp[0]-cx;
        s_pts[wid][lane][1] = xp[1]-cy;
        s_pts[wid][lane][2] = xp[2]-cz;
        const float* fp = f + ((size_t)b*16384 + myi)*3;
        s_pts[wid][lane][3] = fp[0];
        s_pts[wid][lane][4] = fp[1];
        s_pts[wid][lane][5] = fp[2];
    }
    #pragma unroll
    for (int k=0; k<K; ++k){
        float gv = conv_feat6(s_pts[wid][k][0], s_pts[wid][k][1], s_pts[wid][k][2],
                              s_pts[wid][k][3], s_pts[wid][k][4], s_pts[wid][k][5],
                              cwT[0*64+lane], cwT[1*64+lane], cwT[2*64+lane],
                              cwT[3*64+lane], cwT[4*64+lane], cwT[5*64+lane],
                              s_csc[lane], s_cbs[lane]);
        gda[wid][k][lane] = gv - np_o;
    }

    float C = 0.f;
    #pragma unroll
    for (int d=0; d<64; d++) C = fmaf(np_l[wid][d], wt[(64+d)*65 + lane], C);

    float acc_y[K];
    #pragma unroll
    for (int k=0;k<K;k++) acc_y[k] = C;

    #pragma unroll
    for (int c=0; c<2; ++c){
        float wr[32];
        #pragma unroll
        for (int j=0;j<32;j++) wr[j] = wt[(c*32+j)*65 + lane];
        #pragma unroll
        for (int k=0;k<K;k++){
            const float4* g4 = (const float4*)&gda[wid][k][c*32];
            float yk = 0.f;
            #pragma unroll
            for (int j4=0;j4<8;j4++){
                float4 gg = g4[j4];
                yk = fmaf(gg.x, wr[j4*4+0], yk);
                yk = fmaf(gg.y, wr[j4*4+1], yk);
                yk = fmaf(gg.z, wr[j4*4+2], yk);
                yk = fmaf(gg.w, wr[j4*4+3], yk);
            }
            acc_y[k] = acc_y[k] + yk;
        }
    }

    float acc = -1e30f;
    #pragma unroll
    for (int k=0;k<K;k++){
        float v = fmaxf(fmaf(acc_y[k], s_sc[lane], s_bs[lane]), 0.0f);
        acc = fmaxf(acc, v);
    }
    out[((size_t)b*NQ + s)*64 + lane] = acc;
}

// ===================== sa_block (512-thr, wave-parallel softmax) ================
__device__ void sa_block(const float* X, float* Xout,
                         float* Q, float* E, float* XV, float* XR, float* CS,
                         const float* qk_w, const float* v_w, const float* v_b,
                         const float* t_w, const float* t_b,
                         const float* g, const float* bb, int t)
{
    constexpr int NT = 512;
    for (int e=t; e<512; e+=NT){
        int n = e>>4, o = e&15;
        float y = 0.f;
        for (int c=0;c<64;c++) y = fmaf(qk_w[o*64+c], X[c*32+n], y);
        Q[n*16+o] = y;
    }
    for (int e=t; e<2048; e+=NT){
        int o = e>>5, n = e&31;
        float y = v_b[o];
        for (int c=0;c<64;c++) y = fmaf(v_w[o*64+c], X[c*32+n], y);
        XV[o*32+n] = y;
    }
    __syncthreads();
    for (int e=t; e<1024; e+=NT){
        int n = e>>5, m = e&31;
        float y = 0.f;
        for (int d=0;d<16;d++) y = fmaf(Q[n*16+d], Q[m*16+d], y);
        E[e] = y;
    }
    __syncthreads();
    // wave-parallel row softmax: each 32-lane group holds one row
    for (int e=t; e<1024; e+=NT){
        float v = E[e];
        float mx = v;
        #pragma unroll
        for (int mk=16; mk>=1; mk>>=1) mx = fmaxf(mx, __shfl_xor(mx, mk, 64));
        float p = expf(v - mx);
        float sum = p;
        #pragma unroll
        for (int mk=16; mk>=1; mk>>=1) sum += __shfl_xor(sum, mk, 64);
        E[e] = p / sum;
    }
    __syncthreads();
    if (t < 32){
        float cs = 0.f;
        for (int n=0;n<32;n++) cs += E[n*32+t];
        CS[t] = 1e-9f + cs;
    }
    __syncthreads();
    for (int e=t; e<1024; e+=NT) E[e] = E[e] / CS[e&31];
    __syncthreads();
    for (int e=t; e<2048; e+=NT){
        int c = e>>5, m = e&31;
        float y = 0.f;
        for (int n=0;n<32;n++) y = fmaf(XV[c*32+n], E[n*32+m], y);
        XR[c*32+m] = y;
    }
    __syncthreads();
    for (int e=t; e<2048; e+=NT){
        int o = e>>5, n = e&31;
        float y = 0.f;
        for (int c=0;c<64;c++) y = fmaf(t_w[o*64+c], X[c*32+n]-XR[c*32+n], y);
        y += t_b[o];
        y = fmaxf(fmaf(y, bnscale(g[o]), bb[o]), 0.0f);
        Xout[e] = X[e] + y;
    }
    __syncthreads();
}

// ===================== k_mega (proven r7: 512 thr, (512,1)) =====================
__global__ __launch_bounds__(512, 1) void k_mega(
    const float* __restrict__ new_xyz1,   // (b,128,3) centered
    const float* __restrict__ feat,       // (b,128,64)
    const float* __restrict__ l1_w, const float* __restrict__ l1_g, const float* __restrict__ l1_b,
    const float* st_c1_w, const float* st_bn1_g, const float* st_bn1_b,
    const float* st_c2_w, const float* st_bn2_g, const float* st_bn2_b,
    const float* sa1_qk, const float* sa1_v, const float* sa1_vb,
    const float* sa1_t, const float* sa1_tb, const float* sa1_g, const float* sa1_b,
    const float* sa2_qk, const float* sa2_v, const float* sa2_vb,
    const float* sa2_t, const float* sa2_tb, const float* sa2_g, const float* sa2_b,
    const float* fuse_w, const float* fuse_g, const float* fuse_b,
    const float* lin1_w, const float* bn6_g, const float* bn6_b,
    const float* lin2_w, const float* lin2_b,
    float* __restrict__ out)
{
    constexpr int NT = 512;
    __shared__ float nx1[384];
    __shared__ int   s_i2[32];
    __shared__ float np2L[2048];
    __shared__ float nx2[96];
    __shared__ int   s_k2[512];
    __shared__ float wt[8320];
    __shared__ float s_sc[64], s_bs[64];
    __shared__ float smt[15168];          // tail scratch; F1 (stride 33) at 0

    int b = blockIdx.x, t = threadIdx.x, wid = t>>6, lane = t&63;

    // ---- A: stage ----
    for (int e=t; e<384; e+=NT) nx1[e] = new_xyz1[(size_t)b*384 + e];
    for (int e=t; e<8192; e+=NT){ int o = e>>7, d = e&127; wt[d*65 + o] = l1_w[e]; }
    if (t < 64){ s_sc[t] = bnscale(l1_g[t]); s_bs[t] = l1_b[t]; }
    __syncthreads();

    // ---- B: fps2 (128 -> 32), wave 0 only ----
    if (wid == 0){
        float px[2],py[2],pz[2],dist[2];
        #pragma unroll
        for (int i=0;i<2;i++){
            int n = lane + i*64;
            px[i]=nx1[n*3+0]; py[i]=nx1[n*3+1]; pz[i]=nx1[n*3+2];
            dist[i]=1e10f;
        }
        if (lane==0) s_i2[0] = 0;
        float cx=nx1[0], cy=nx1[1], cz=nx1[2];
        for (int it=1; it<32; ++it){
            float bv=-1.0f; int bi=0;
            float bx=0.f, by=0.f, bz=0.f;
            #pragma unroll
            for (int i=0;i<2;i++){
                float d = fpsdist(px[i]-cx, py[i]-cy, pz[i]-cz);
                float nd = fminf(dist[i], d);
                dist[i]=nd;
                bool better = nd > bv;
                bv = better ? nd : bv;
                bi = better ? (lane + i*64) : bi;
                bx = better ? px[i] : bx;
                by = better ? py[i] : by;
                bz = better ? pz[i] : bz;
            }
            unsigned long long key = ((unsigned long long)__float_as_uint(bv) << 32)
                                   | (unsigned long long)(unsigned)(~(unsigned)bi);
            #pragma unroll
            for (int off=32; off>=1; off>>=1){
                unsigned long long ok = u64_shfl_down(key, off);
                float ox = __shfl_down(bx, off, 64);
                float oy = __shfl_down(by, off, 64);
                float oz = __shfl_down(bz, off, 64);
                bool better = ok > key;
                key = better ? ok : key;
                bx = better ? ox : bx;
                by = better ? oy : by;
                bz = better ? oz : bz;
            }
            key = u64_bcast0(key);
            cx = __shfl(bx, 0, 64); cy = __shfl(by, 0, 64); cz = __shfl(bz, 0, 64);
            if (lane==0) s_i2[it] = (int)(~(unsigned)(key & 0xFFFFFFFFull));
        }
    }
    __syncthreads();

    // ---- C: gather2 ----
    for (int e=t; e<2048; e+=NT){
        int s = e>>6, o = e&63;
        np2L[s*64 + o] = feat[((size_t)b*128 + s_i2[s])*64 + o];
    }
    if (t < 32){
        int idx = s_i2[t];
        nx2[t*3+0] = nx1[idx*3+0];
        nx2[t*3+1] = nx1[idx*3+1];
        nx2[t*3+2] = nx1[idx*3+2];
    }
    __syncthreads();

    // ---- D: knn2 (32 queries x top-16 of 128), 4 queries per wave ----
    for (int j=0;j<4;j++){
        int s = wid + 8*j;
        float qx = nx2[s*3+0], qy = nx2[s*3+1], qz = nx2[s*3+2];
        float qs = sumsq3(qx,qy,qz);
        unsigned long long pp0, pp1;
        {
            float ax=nx1[lane*3+0], ay=nx1[lane*3+1], az=nx1[lane*3+2];
            pp0 = packdi(sqdist3(qx,qy,qz,qs,ax,ay,az), (unsigned)lane);
            ax=nx1[(lane+64)*3+0]; ay=nx1[(lane+64)*3+1]; az=nx1[(lane+64)*3+2];
            pp1 = packdi(sqdist3(qx,qy,qz,qs,ax,ay,az), (unsigned)(lane+64));
        }
        for (int r=0; r<16; ++r){
            unsigned long long mm = u64min(pp0, pp1);
            #pragma unroll
            for (int off=32; off>=1; off>>=1) mm = u64min(mm, u64_shfl_down(mm, off));
            unsigned long long win = u64_bcast0(mm);
            if (lane==0) s_k2[s*16 + r] = (int)(win & 0xFFFFFFFFull);
            if (pp0 == win) pp0 = ~0ull;
            if (pp1 == win) pp1 = ~0ull;
        }
    }
    __syncthreads();

    // ---- E: group_local<16>, 4 queries per wave ----
    float* gda = smt + 2112;     // aliases XA/XB (4096 floats), dead until tail
    for (int j=0;j<4;j++){
        int s = wid + 8*j;
        float np_o = np2L[s*64 + lane];
        float C0 = 0.f;
        #pragma unroll
        for (int d=0; d<64; d++) C0 = fmaf(np2L[s*64 + d], wt[(64+d)*65 + lane], C0);
        float acc_y[16];
        #pragma unroll
        for (int k=0;k<16;k++) acc_y[k] = C0;
        #pragma unroll
        for (int half=0; half<2; ++half){
            #pragma unroll
            for (int kk=0;kk<8;++kk){
                int ik = s_k2[s*16 + half*8 + kk];
                gda[(wid*8+kk)*64 + lane] = feat[((size_t)b*128 + ik)*64 + lane] - np_o;
            }
            #pragma unroll
            for (int c=0; c<2; ++c){
                float wr[32];
                #pragma unroll
                for (int jj=0;jj<32;jj++) wr[jj] = wt[(c*32+jj)*65 + lane];
                #pragma unroll
                for (int kk=0;kk<8;++kk){
                    const float4* g4 = (const float4*)&gda[(wid*8+kk)*64 + c*32];
                    float yk = 0.f;
                    #pragma unroll
                    for (int j4=0;j4<8;j4++){
                        float4 gg = g4[j4];
                        yk = fmaf(gg.x, wr[j4*4+0], yk);
                        yk = fmaf(gg.y, wr[j4*4+1], yk);
                        yk = fmaf(gg.z, wr[j4*4+2], yk);
                        yk = fmaf(gg.w, wr[j4*4+3], yk);
                    }
                    acc_y[half*8+kk] = acc_y[half*8+kk] + yk;
                }
            }
        }
        float acc = -1e30f;
        #pragma unroll
        for (int k=0;k<16;k++){
            float v = fmaxf(fmaf(acc_y[k], s_sc[lane], s_bs[lane]), 0.0f);
            acc = fmaxf(acc, v);
        }
        smt[lane*33 + s] = acc;     // F1[c=lane][n=s], stride 33
    }
    __syncthreads();

    // ---- F: tail ----
    float* F1 = smt;            // stride 33, [0,2112)
    float* XA = smt + 2112;
    float* XB = smt + 4160;
    float* Q  = smt + 6208;
    float* E  = smt + 6720;
    float* XV = smt + 7744;
    float* XR = smt + 9792;
    float* CS = smt + 11840;
    float* FO = smt + 6208;     // 256x33 = 8448 (reuses SA scratch)
    float* PO = smt + 14656;
    float* P2 = smt + 14912;

    for (int e=t; e<2048; e+=NT){
        int o = e>>5, n = e&31;
        float y = 0.f;
        for (int c=0;c<64;c++) y = fmaf(st_c1_w[o*64+c], F1[c*33+n], y);
        XA[e] = fmaxf(fmaf(y, bnscale(st_bn1_g[o]), st_bn1_b[o]), 0.0f);
    }
    __syncthreads();
    for (int e=t; e<2048; e+=NT){
        int o = e>>5, n = e&31;
        float y = 0.f;
        for (int c=0;c<64;c++) y = fmaf(st_c2_w[o*64+c], XA[c*32+n], y);
        XB[e] = fmaxf(fmaf(y, bnscale(st_bn2_g[o]), st_bn2_b[o]), 0.0f);
    }
    __syncthreads();
    sa_block(XB, XA, Q,E,XV,XR,CS, sa1_qk, sa1_v, sa1_vb, sa1_t, sa1_tb, sa1_g, sa1_b, t);
    sa_block(XA, XB, Q,E,XV,XR,CS, sa2_qk, sa2_v, sa2_vb, sa2_t, sa2_tb, sa2_g, sa2_b, t);
    for (int e=t; e<8192; e+=NT){
        int o = e>>5, n = e&31;
        const float* wr = fuse_w + o*192;
        float y = 0.f;
        for (int c=0;c<64;c++) y = fmaf(wr[c],      XA[c*32+n], y);
        for (int c=0;c<64;c++) y = fmaf(wr[64+c],   XB[c*32+n], y);
        for (int c=0;c<64;c++) y = fmaf(wr[128+c],  F1[c*33+n], y);
        float v = fmaf(y, bnscale(fuse_g[o]), fuse_b[o]);
        FO[o*33+n] = (v > 0.0f) ? v : 0.2f*v;
    }
    __syncthreads();
    if (t < 256){
        float mx = -1e30f;
        for (int n=0;n<32;n++) mx = fmaxf(mx, FO[t*33+n]);
        PO[t] = mx;
    }
    __syncthreads();
    if (t < 256){
        const float* wr = lin1_w + t*256;
        float y = 0.f;
        for (int c=0;c<256;c++) y = fmaf(wr[c], PO[c], y);
        P2[t] = fmaxf(fmaf(y, bnscale(bn6_g[t]), bn6_b[t]), 0.0f);
    }
    __syncthreads();
    if (t < 256){
        const float* wr = lin2_w + t*256;
        float y = 0.f;
        for (int c=0;c<256;c++) y = fmaf(wr[c], P2[c], y);
        out[96 + b*256 + t] = y + lin2_b[t];
    }
}

// ===================== launch =====================
extern "C" void kernel_launch(void* const* d_in, const int* in_sizes, int n_in,
                              void* d_out, int out_size, void* d_ws, size_t ws_size,
                              hipStream_t stream)
{
    const float* xyz      = (const float*)d_in[0];
    const float* f        = (const float*)d_in[1];
    const float* conv1_w  = (const float*)d_in[2];
    const float* bn1_g    = (const float*)d_in[3];
    const float* bn1_b    = (const float*)d_in[4];
    const float* l0_w     = (const float*)d_in[5];
    const float* l0_g     = (const float*)d_in[6];
    const float* l0_b     = (const float*)d_in[7];
    const float* l1_w     = (const float*)d_in[8];
    const float* l1_g     = (const float*)d_in[9];
    const float* l1_b     = (const float*)d_in[10];
    const float* st_c1_w  = (const float*)d_in[11];
    const float* st_bn1_g = (const float*)d_in[12];
    const float* st_bn1_b = (const float*)d_in[13];
    const float* st_c2_w  = (const float*)d_in[14];
    const float* st_bn2_g = (const float*)d_in[15];
    const float* st_bn2_b = (const float*)d_in[16];
    const float* sa1_qk   = (const float*)d_in[17];
    const float* sa1_v    = (const float*)d_in[18];
    const float* sa1_vb   = (const float*)d_in[19];
    const float* sa1_t    = (const float*)d_in[20];
    const float* sa1_tb   = (const float*)d_in[21];
    const float* sa1_g    = (const float*)d_in[22];
    const float* sa1_b    = (const float*)d_in[23];
    const float* sa2_qk   = (const float*)d_in[24];
    const float* sa2_v    = (const float*)d_in[25];
    const float* sa2_vb   = (const float*)d_in[26];
    const float* sa2_t    = (const float*)d_in[27];
    const float* sa2_tb   = (const float*)d_in[28];
    const float* sa2_g    = (const float*)d_in[29];
    const float* sa2_b    = (const float*)d_in[30];
    const float* fuse_w   = (const float*)d_in[31];
    const float* fuse_g   = (const float*)d_in[32];
    const float* fuse_b   = (const float*)d_in[33];
    const float* lin1_w   = (const float*)d_in[34];
    const float* bn6_g    = (const float*)d_in[35];
    const float* bn6_b    = (const float*)d_in[36];
    const float* lin2_w   = (const float*)d_in[37];
    const float* lin2_b   = (const float*)d_in[38];
    float* out = (float*)d_out;

    float* ws = (float*)d_ws;
    float* center   = ws + 0;        // 96
    float* new_xyz1 = ws + 96;       // 12288
    float* np1      = ws + 12384;    // 262144
    float* feat     = ws + 274528;   // 262144
    int*   fps1     = (int*)(ws + 536672);  // 4096
    int*   knn1     = (int*)(ws + 540768);  // 131072

    k_fps1<<<32, 512, 0, stream>>>(xyz, center, out, fps1);
    k_knn1<<<1024, 256, 0, stream>>>(xyz, f, center, conv1_w, bn1_g, bn1_b,
                                     fps1, new_xyz1, np1, knn1);
    k_group_local<32,128><<<1024, 256, 0, stream>>>(
        xyz, f, center, conv1_w, bn1_g, bn1_b, knn1, np1, l0_w, l0_g, l0_b, feat);
    k_mega<<<32, 512, 0, stream>>>(new_xyz1, feat,
        l1_w, l1_g, l1_b,
        st_c1_w, st_bn1_g, st_bn1_b, st_c2_w, st_bn2_g, st_bn2_b,
        sa1_qk, sa1_v, sa1_vb, sa1_t, sa1_tb, sa1_g, sa1_b,
        sa2_qk, sa2_v, sa2_vb, sa2_t, sa2_tb, sa2_g, sa2_b,
        fuse_w, fuse_g, fuse_b, lin1_w, bn6_g, bn6_b, lin2_w, lin2_b, out);
}